// Round 1
// baseline (881.707 us; speedup 1.0000x reference)
//
#include <hip/hip_runtime.h>
#include <math.h>

#define N_NODES 50000
#define N_EDGES 600000
#define HDIM 128
#define NCLS 10
#define NGRAPH 500
#define BN_EPS 1e-5f

// ---------------------------------------------------------------------------
// Column stats: stats[0..127] += column sums, stats[128..255] += column sumsq
// ---------------------------------------------------------------------------
__global__ void colstats_kernel(const float* __restrict__ X, int M, float* __restrict__ stats) {
    int col = threadIdx.x & 127;
    int sub = threadIdx.x >> 7;  // 0/1 -> two rows per block-iteration
    float s = 0.f, sq = 0.f;
    for (int r = blockIdx.x * 2 + sub; r < M; r += gridDim.x * 2) {
        float v = X[(size_t)r * HDIM + col];
        s += v; sq += v * v;
    }
    atomicAdd(&stats[col], s);
    atomicAdd(&stats[HDIM + col], sq);
}

// ---------------------------------------------------------------------------
// CSR build: histogram over dst, exclusive scan (single block), scatter fill
// ---------------------------------------------------------------------------
__global__ void hist_kernel(const int* __restrict__ ei, int* __restrict__ counts) {
    int e = blockIdx.x * 256 + threadIdx.x;
    if (e < N_EDGES) atomicAdd(&counts[ei[N_EDGES + e]], 1);
}

__global__ __launch_bounds__(1024) void scan_kernel(const int* __restrict__ counts, int n,
                                                    int* __restrict__ offsets, int* __restrict__ cursor) {
    __shared__ int tot[1024];
    const int tid = threadIdx.x;
    const int CH = (n + 1023) / 1024;
    int base = tid * CH;
    int s = 0;
    for (int j = 0; j < CH; j++) {
        int i = base + j;
        if (i < n) s += counts[i];
    }
    tot[tid] = s;
    __syncthreads();
    for (int off = 1; off < 1024; off <<= 1) {
        int v = (tid >= off) ? tot[tid - off] : 0;
        __syncthreads();
        tot[tid] += v;
        __syncthreads();
    }
    int run = (tid == 0) ? 0 : tot[tid - 1];  // exclusive base for this chunk
    for (int j = 0; j < CH; j++) {
        int i = base + j;
        if (i < n) {
            offsets[i] = run;
            cursor[i] = run;
            run += counts[i];
        }
    }
    if (tid == 1023) offsets[n] = tot[1023];
}

__global__ void fill_kernel(const int* __restrict__ ei, int* __restrict__ cursor, int* __restrict__ csr) {
    int e = blockIdx.x * 256 + threadIdx.x;
    if (e < N_EDGES) {
        int d = ei[N_EDGES + e];
        int pos = atomicAdd(&cursor[d], 1);
        csr[pos] = ei[e];  // src
    }
}

// ---------------------------------------------------------------------------
// GIN aggregation: z[n] = h[n] + sum_{src->n} h[src].  One wave per node,
// lane owns 2 columns (float2), neighbor list broadcast via shfl.
// ---------------------------------------------------------------------------
__global__ __launch_bounds__(256) void agg_kernel(const float* __restrict__ h,
                                                  const int* __restrict__ offsets,
                                                  const int* __restrict__ csr,
                                                  float* __restrict__ z) {
    int node = (blockIdx.x * 256 + threadIdx.x) >> 6;
    int lane = threadIdx.x & 63;
    if (node >= N_NODES) return;
    int c0 = lane * 2;
    int beg = offsets[node], end = offsets[node + 1];
    const float2 self = *(const float2*)&h[(size_t)node * HDIM + c0];
    float ax = self.x, ay = self.y;
    for (int j = beg; j < end; j += 64) {
        int cnt = min(64, end - j);
        int sl = (j + lane < end) ? csr[j + lane] : 0;
        for (int t = 0; t < cnt; t++) {
            int s = __shfl(sl, t, 64);
            const float2 hv = *(const float2*)&h[(size_t)s * HDIM + c0];
            ax += hv.x; ay += hv.y;
        }
    }
    float2 o; o.x = ax; o.y = ay;
    *(float2*)&z[(size_t)node * HDIM + c0] = o;
}

// ---------------------------------------------------------------------------
// segment_sum via atomics (batch sorted, contention ~100 nodes/graph)
// ---------------------------------------------------------------------------
__global__ __launch_bounds__(256) void segsum_kernel(const float* __restrict__ h,
                                                     const int* __restrict__ batch,
                                                     float* __restrict__ g) {
    int node = (blockIdx.x * 256 + threadIdx.x) >> 6;
    int lane = threadIdx.x & 63;
    if (node >= N_NODES) return;
    int b = batch[node];
    int c0 = lane * 2;
    const float2 hv = *(const float2*)&h[(size_t)node * HDIM + c0];
    atomicAdd(&g[b * HDIM + c0], hv.x);
    atomicAdd(&g[b * HDIM + c0 + 1], hv.y);
}

// ---------------------------------------------------------------------------
// Fused GEMM: C[M,128] = op(A)[M,128] @ op(B)[128,128] + bias_eff, with
//  PRE_A : A' = relu(A*aCol + bCol)   (BN+relu on A columns, from statsPre)
//  PRE_B : B' = diag(aCol)B, bias_eff = bias + bCol@B   (fold BN left of B)
//  RELU  : C = relu(C)
//  STATS : statsOut += column sums / sumsq of C (post-bias, post-RELU)
// Tile: BM=64, BN=128, BK=64; 256 threads; 4x8 micro-tile (rows ty+16i).
// In-place C==A is safe: all A reads precede all C writes, rows block-disjoint.
// ---------------------------------------------------------------------------
template <bool PRE_A, bool PRE_B, bool RELU, bool STATS>
__global__ __launch_bounds__(256, 3) void gemm_bn(const float* A, const float* __restrict__ B,
                                                  const float* __restrict__ bias, float* C, int M,
                                                  const float* __restrict__ statsPre,
                                                  const float* __restrict__ gammaPre,
                                                  const float* __restrict__ betaPre,
                                                  float invCnt, float* __restrict__ statsOut) {
    __shared__ float At[64][65];    // A transposed: At[k][row], +1 pad (scalar reads)
    __shared__ float Bs[64][128];   // Bs[k][n]
    __shared__ float aPre[128], bPre[128];

    const int tid = threadIdx.x;
    const int tx = tid & 15, ty = tid >> 4;
    const int r0 = blockIdx.x * 64;

    if (PRE_A || PRE_B) {
        if (tid < 128) {
            float m = statsPre[tid] * invCnt;
            float v = statsPre[128 + tid] * invCnt - m * m;
            float a = gammaPre[tid] * rsqrtf(v + BN_EPS);
            aPre[tid] = a;
            bPre[tid] = betaPre[tid] - m * a;
        }
        __syncthreads();
    }

    float acc[4][8];
#pragma unroll
    for (int i = 0; i < 4; i++)
#pragma unroll
        for (int j = 0; j < 8; j++) acc[i][j] = 0.f;

    float biasEff[8];
#pragma unroll
    for (int j = 0; j < 8; j++) biasEff[j] = bias[8 * tx + j];
    if (PRE_B) {
        // bias_eff[n] += sum_k bPre[k] * B[k][n]  (original B, from global/L2)
        for (int k = 0; k < 128; k++) {
            float bb = bPre[k];
            const float* Brow = B + (size_t)k * HDIM + 8 * tx;
#pragma unroll
            for (int j = 0; j < 8; j++) biasEff[j] = fmaf(bb, Brow[j], biasEff[j]);
        }
    }

    for (int kc = 0; kc < 128; kc += 64) {
        // stage A tile (64 rows x 64 k) transposed, optional BN+relu transform
#pragma unroll
        for (int i = 0; i < 4; i++) {
            int f4 = tid + i * 256;
            int row = f4 >> 4;
            int kg = f4 & 15;
            int grow = r0 + row;
            float4 av;
            if (grow < M) av = *(const float4*)(A + (size_t)grow * HDIM + kc + kg * 4);
            else av = make_float4(0.f, 0.f, 0.f, 0.f);
            if (PRE_A) {
                int kb = kc + kg * 4;
                av.x = fmaxf(fmaf(av.x, aPre[kb + 0], bPre[kb + 0]), 0.f);
                av.y = fmaxf(fmaf(av.y, aPre[kb + 1], bPre[kb + 1]), 0.f);
                av.z = fmaxf(fmaf(av.z, aPre[kb + 2], bPre[kb + 2]), 0.f);
                av.w = fmaxf(fmaf(av.w, aPre[kb + 3], bPre[kb + 3]), 0.f);
            }
            At[kg * 4 + 0][row] = av.x;
            At[kg * 4 + 1][row] = av.y;
            At[kg * 4 + 2][row] = av.z;
            At[kg * 4 + 3][row] = av.w;
        }
        // stage B tile (64 k x 128 n), optional column scale
#pragma unroll
        for (int i = 0; i < 8; i++) {
            int f4 = tid + i * 256;
            int krow = f4 >> 5;
            int cg = f4 & 31;
            float4 bv = *(const float4*)(B + (size_t)(kc + krow) * HDIM + cg * 4);
            if (PRE_B) {
                float s = aPre[kc + krow];
                bv.x *= s; bv.y *= s; bv.z *= s; bv.w *= s;
            }
            *(float4*)&Bs[krow][cg * 4] = bv;
        }
        __syncthreads();
#pragma unroll 8
        for (int k = 0; k < 64; k++) {
            float av[4];
            av[0] = At[k][ty];
            av[1] = At[k][ty + 16];
            av[2] = At[k][ty + 32];
            av[3] = At[k][ty + 48];
            const float4 b0 = *(const float4*)&Bs[k][8 * tx];
            const float4 b1 = *(const float4*)&Bs[k][8 * tx + 4];
            float bv[8] = {b0.x, b0.y, b0.z, b0.w, b1.x, b1.y, b1.z, b1.w};
#pragma unroll
            for (int i = 0; i < 4; i++)
#pragma unroll
                for (int j = 0; j < 8; j++) acc[i][j] = fmaf(av[i], bv[j], acc[i][j]);
        }
        __syncthreads();
    }

    float s[8], sq[8];
    if (STATS) {
#pragma unroll
        for (int j = 0; j < 8; j++) { s[j] = 0.f; sq[j] = 0.f; }
    }
#pragma unroll
    for (int i = 0; i < 4; i++) {
        int grow = r0 + ty + 16 * i;
        if (grow < M) {
            float v[8];
#pragma unroll
            for (int j = 0; j < 8; j++) {
                v[j] = acc[i][j] + biasEff[j];
                if (RELU) v[j] = fmaxf(v[j], 0.f);
                if (STATS) { s[j] += v[j]; sq[j] += v[j] * v[j]; }
            }
            float4 o0 = make_float4(v[0], v[1], v[2], v[3]);
            float4 o1 = make_float4(v[4], v[5], v[6], v[7]);
            *(float4*)(C + (size_t)grow * HDIM + 8 * tx) = o0;
            *(float4*)(C + (size_t)grow * HDIM + 8 * tx + 4) = o1;
        }
    }
    if (STATS) {
        float* red = &At[0][0];  // 4160 floats >= 4096; main loop done with At
#pragma unroll
        for (int j = 0; j < 8; j++) {
            red[ty * 128 + 8 * tx + j] = s[j];
            red[2048 + ty * 128 + 8 * tx + j] = sq[j];
        }
        __syncthreads();
        if (tid < 128) {
            float t = 0.f;
#pragma unroll
            for (int u = 0; u < 16; u++) t += red[u * 128 + tid];
            atomicAdd(&statsOut[tid], t);
        } else {
            int col = tid - 128;
            float t = 0.f;
#pragma unroll
            for (int u = 0; u < 16; u++) t += red[2048 + u * 128 + col];
            atomicAdd(&statsOut[128 + col], t);
        }
    }
}

// ---------------------------------------------------------------------------
// Head: logits = BN(g2)@W_cls + b_cls (BN folded), then log_softmax. One row
// per thread; fold computed redundantly per block (tiny).
// ---------------------------------------------------------------------------
__global__ __launch_bounds__(256) void head_kernel(const float* __restrict__ g2,
                                                   const float* __restrict__ stats,
                                                   const float* __restrict__ gamma,
                                                   const float* __restrict__ beta,
                                                   const float* __restrict__ Wc,
                                                   const float* __restrict__ bc,
                                                   float* __restrict__ out, float invCnt) {
    __shared__ float Wf[HDIM * NCLS];
    __shared__ float bf[NCLS];
    __shared__ float aP[HDIM], bP[HDIM];
    const int tid = threadIdx.x;
    if (tid < HDIM) {
        float m = stats[tid] * invCnt;
        float v = stats[HDIM + tid] * invCnt - m * m;
        float a = gamma[tid] * rsqrtf(v + BN_EPS);
        aP[tid] = a;
        bP[tid] = beta[tid] - m * a;
    }
    __syncthreads();
    for (int idx = tid; idx < HDIM * NCLS; idx += 256) {
        int k = idx / NCLS;
        Wf[idx] = aP[k] * Wc[idx];
    }
    if (tid < NCLS) {
        float sv = bc[tid];
        for (int k = 0; k < HDIM; k++) sv = fmaf(bP[k], Wc[k * NCLS + tid], sv);
        bf[tid] = sv;
    }
    __syncthreads();
    int row = blockIdx.x * 256 + tid;
    if (row >= NGRAPH) return;
    float l[NCLS];
#pragma unroll
    for (int c = 0; c < NCLS; c++) l[c] = bf[c];
    for (int k = 0; k < HDIM; k++) {
        float gv = g2[row * HDIM + k];
#pragma unroll
        for (int c = 0; c < NCLS; c++) l[c] = fmaf(gv, Wf[k * NCLS + c], l[c]);
    }
    float mx = l[0];
#pragma unroll
    for (int c = 1; c < NCLS; c++) mx = fmaxf(mx, l[c]);
    float se = 0.f;
#pragma unroll
    for (int c = 0; c < NCLS; c++) se += expf(l[c] - mx);
    float lse = mx + logf(se);
#pragma unroll
    for (int c = 0; c < NCLS; c++) out[row * NCLS + c] = l[c] - lse;
}

// ---------------------------------------------------------------------------
extern "C" void kernel_launch(void* const* d_in, const int* in_sizes, int n_in,
                              void* d_out, int out_size, void* d_ws, size_t ws_size,
                              hipStream_t stream) {
    const float* x          = (const float*)d_in[0];
    const int*   ei         = (const int*)d_in[1];
    const int*   batch      = (const int*)d_in[2];
    const float* gamma_feat = (const float*)d_in[3];
    const float* beta_feat  = (const float*)d_in[4];
    const float* W_feat     = (const float*)d_in[5];
    const float* b_feat     = (const float*)d_in[6];
    const float* gin_W1     = (const float*)d_in[7];
    const float* gin_b1     = (const float*)d_in[8];
    const float* gin_gamma  = (const float*)d_in[9];
    const float* gin_beta   = (const float*)d_in[10];
    const float* gin_W2     = (const float*)d_in[11];
    const float* gin_b2     = (const float*)d_in[12];
    const float* gamma_fc   = (const float*)d_in[13];
    const float* beta_fc    = (const float*)d_in[14];
    const float* W_fc       = (const float*)d_in[15];
    const float* b_fc       = (const float*)d_in[16];
    const float* gamma_h    = (const float*)d_in[17];
    const float* beta_h     = (const float*)d_in[18];
    const float* W_cls      = (const float*)d_in[19];
    const float* b_cls      = (const float*)d_in[20];
    float* out = (float*)d_out;

    float* ws = (float*)d_ws;
    size_t off = 0;
    float* h  = ws + off; off += (size_t)N_NODES * HDIM;
    float* zy = ws + off; off += (size_t)N_NODES * HDIM;   // z and y alias (in-place gemm)
    float* g2 = ws + off; off += NGRAPH * HDIM;
    size_t zstart = off;                                    // ---- zeroed region ----
    float* g = ws + off; off += NGRAPH * HDIM;
    float* stats = ws + off; off += 256 * 6;
    int* counts = (int*)(ws + off); off += N_NODES;
    size_t zbytes = (off - zstart) * sizeof(float);         // ---- end zeroed ----
    int* offsets = (int*)(ws + off); off += N_NODES + 1;
    int* cursor  = (int*)(ws + off); off += N_NODES;
    int* csr     = (int*)(ws + off); off += N_EDGES;

    float* statsX  = stats;
    float* statsY0 = stats + 256;
    float* statsY1 = stats + 512;
    float* statsY2 = stats + 768;
    float* statsYa[3] = {statsY0, statsY1, statsY2};
    float* statsG  = stats + 1024;
    float* statsG2 = stats + 1280;

    hipMemsetAsync(g, 0, zbytes, stream);

    const float invN = 1.f / (float)N_NODES;
    const float invG = 1.f / (float)NGRAPH;
    const int gblocks = (N_NODES + 63) / 64;       // 782
    const int eblocks = (N_EDGES + 255) / 256;     // 2344
    const int nwaves  = (N_NODES * 64 + 255) / 256;  // 12500

    // BN(x) stats + CSR build
    colstats_kernel<<<256, 256, 0, stream>>>(x, N_NODES, statsX);
    hist_kernel<<<eblocks, 256, 0, stream>>>(ei, counts);
    scan_kernel<<<1, 1024, 0, stream>>>(counts, N_NODES, offsets, cursor);
    fill_kernel<<<eblocks, 256, 0, stream>>>(ei, cursor, csr);

    // h = relu(BN(x) @ W_feat + b_feat)   [BN folded into B]
    gemm_bn<false, true, true, false><<<gblocks, 256, 0, stream>>>(
        x, W_feat, b_feat, h, N_NODES, statsX, gamma_feat, beta_feat, invN, nullptr);

    for (int i = 0; i < 3; i++) {
        // z = h + sum_neighbors h
        agg_kernel<<<nwaves, 256, 0, stream>>>(h, offsets, csr, zy);
        // y = z @ W1 + b1  (in-place, + column stats of y)
        gemm_bn<false, false, false, true><<<gblocks, 256, 0, stream>>>(
            zy, gin_W1 + i * HDIM * HDIM, gin_b1 + i * HDIM, zy, N_NODES,
            nullptr, nullptr, nullptr, invN, statsYa[i]);
        // h = relu( relu(BN(y)) @ W2 + b2 )  [BN+relu applied to A at staging]
        gemm_bn<true, false, true, false><<<gblocks, 256, 0, stream>>>(
            zy, gin_W2 + i * HDIM * HDIM, gin_b2 + i * HDIM, h, N_NODES,
            statsYa[i], gin_gamma + i * HDIM, gin_beta + i * HDIM, invN, nullptr);
    }

    // g = segment_sum(h, batch)
    segsum_kernel<<<nwaves, 256, 0, stream>>>(h, batch, g);
    colstats_kernel<<<8, 256, 0, stream>>>(g, NGRAPH, statsG);
    // g2 = relu(BN(g) @ W_fc + b_fc) + stats of g2
    gemm_bn<false, true, true, true><<<(NGRAPH + 63) / 64, 256, 0, stream>>>(
        g, W_fc, b_fc, g2, NGRAPH, statsG, gamma_fc, beta_fc, invG, statsG2);
    // logits = BN(g2) @ W_cls + b_cls -> log_softmax
    head_kernel<<<2, 256, 0, stream>>>(g2, statsG2, gamma_h, beta_h, W_cls, b_cls, out, invG);
}

// Round 5
// 737.363 us; speedup vs baseline: 1.1958x; 1.1958x over previous
//
#include <hip/hip_runtime.h>
#include <math.h>

#define N_NODES 50000
#define N_EDGES 600000
#define HDIM 128
#define NCLS 10
#define NGRAPH 500
#define BN_EPS 1e-5f
#define SCAN_BLOCKS 196  // ceil(N_NODES/256)

// ---------------------------------------------------------------------------
// Column stats: stats[0..127] += column sums, stats[128..255] += column sumsq
// ---------------------------------------------------------------------------
__global__ void colstats_kernel(const float* __restrict__ X, int M, float* __restrict__ stats) {
    int col = threadIdx.x & 127;
    int sub = threadIdx.x >> 7;  // 0/1 -> two rows per block-iteration
    float s = 0.f, sq = 0.f;
    for (int r = blockIdx.x * 2 + sub; r < M; r += gridDim.x * 2) {
        float v = X[(size_t)r * HDIM + col];
        s += v; sq += v * v;
    }
    atomicAdd(&stats[col], s);
    atomicAdd(&stats[HDIM + col], sq);
}

// ---------------------------------------------------------------------------
// CSR build: histogram over dst, 3-level multiblock exclusive scan, scatter
// ---------------------------------------------------------------------------
__global__ void hist_kernel(const int* __restrict__ ei, int* __restrict__ counts) {
    int e = blockIdx.x * 256 + threadIdx.x;
    if (e < N_EDGES) atomicAdd(&counts[ei[N_EDGES + e]], 1);
}

// block-local exclusive scan; per-block totals out
__global__ __launch_bounds__(256) void scan1_kernel(const int* __restrict__ counts,
                                                    int* __restrict__ partial,
                                                    int* __restrict__ blockSums) {
    __shared__ int tmp[256];
    int tid = threadIdx.x;
    int i = blockIdx.x * 256 + tid;
    int v = (i < N_NODES) ? counts[i] : 0;
    tmp[tid] = v;
    __syncthreads();
#pragma unroll
    for (int off = 1; off < 256; off <<= 1) {
        int t = (tid >= off) ? tmp[tid - off] : 0;
        __syncthreads();
        tmp[tid] += t;
        __syncthreads();
    }
    if (i < N_NODES) partial[i] = tmp[tid] - v;  // exclusive within block
    if (tid == 255) blockSums[blockIdx.x] = tmp[255];
}

// single-block scan of the 196 block sums -> exclusive block bases
__global__ __launch_bounds__(256) void scan2_kernel(const int* __restrict__ blockSums,
                                                    int* __restrict__ blockBase) {
    __shared__ int tmp[256];
    int tid = threadIdx.x;
    int v = (tid < SCAN_BLOCKS) ? blockSums[tid] : 0;
    tmp[tid] = v;
    __syncthreads();
#pragma unroll
    for (int off = 1; off < 256; off <<= 1) {
        int t = (tid >= off) ? tmp[tid - off] : 0;
        __syncthreads();
        tmp[tid] += t;
        __syncthreads();
    }
    if (tid < SCAN_BLOCKS) blockBase[tid] = tmp[tid] - v;
}

// add block bases; init cursor; offsets[N] is the constant E
__global__ __launch_bounds__(256) void scan3_kernel(const int* __restrict__ partial,
                                                    const int* __restrict__ blockBase,
                                                    int* __restrict__ offsets,
                                                    int* __restrict__ cursor) {
    int i = blockIdx.x * 256 + threadIdx.x;
    if (i < N_NODES) {
        int o = partial[i] + blockBase[blockIdx.x];
        offsets[i] = o;
        cursor[i] = o;
    }
    if (i == 0) offsets[N_NODES] = N_EDGES;
}

__global__ void fill_kernel(const int* __restrict__ ei, int* __restrict__ cursor, int* __restrict__ csr) {
    int e = blockIdx.x * 256 + threadIdx.x;
    if (e < N_EDGES) {
        int d = ei[N_EDGES + e];
        int pos = atomicAdd(&cursor[d], 1);
        csr[pos] = ei[e];  // src
    }
}

// ---------------------------------------------------------------------------
// GIN aggregation: z[n] = h[n] + sum_{src->n} h[src].  One wave per node,
// lane owns 2 columns (float2); neighbor ids broadcast via shfl; 4x unroll
// keeps 4 independent row loads in flight (latency hiding).
// ---------------------------------------------------------------------------
__global__ __launch_bounds__(256) void agg_kernel(const float* __restrict__ h,
                                                  const int* __restrict__ offsets,
                                                  const int* __restrict__ csr,
                                                  float* __restrict__ z) {
    int node = (blockIdx.x * 256 + threadIdx.x) >> 6;
    int lane = threadIdx.x & 63;
    if (node >= N_NODES) return;
    int c0 = lane * 2;
    int beg = offsets[node], end = offsets[node + 1];
    const float2 self = *(const float2*)&h[(size_t)node * HDIM + c0];
    float ax = self.x, ay = self.y;
    for (int j = beg; j < end; j += 64) {
        int cnt = min(64, end - j);
        int sl = (j + lane < end) ? csr[j + lane] : 0;
        int t = 0;
        for (; t + 4 <= cnt; t += 4) {
            int s0 = __shfl(sl, t, 64);
            int s1 = __shfl(sl, t + 1, 64);
            int s2 = __shfl(sl, t + 2, 64);
            int s3 = __shfl(sl, t + 3, 64);
            float2 v0 = *(const float2*)&h[(size_t)s0 * HDIM + c0];
            float2 v1 = *(const float2*)&h[(size_t)s1 * HDIM + c0];
            float2 v2 = *(const float2*)&h[(size_t)s2 * HDIM + c0];
            float2 v3 = *(const float2*)&h[(size_t)s3 * HDIM + c0];
            ax += v0.x + v1.x + v2.x + v3.x;
            ay += v0.y + v1.y + v2.y + v3.y;
        }
        for (; t < cnt; t++) {
            int s = __shfl(sl, t, 64);
            float2 hv = *(const float2*)&h[(size_t)s * HDIM + c0];
            ax += hv.x; ay += hv.y;
        }
    }
    float2 o; o.x = ax; o.y = ay;
    *(float2*)&z[(size_t)node * HDIM + c0] = o;
}

// ---------------------------------------------------------------------------
// segment_sum without atomics: batch is sorted, so block b binary-searches
// its node range [lb(b), lb(b+1)) and reduces columns directly.
// ---------------------------------------------------------------------------
__global__ __launch_bounds__(128) void segsum2_kernel(const float* __restrict__ h,
                                                      const int* __restrict__ batch,
                                                      float* __restrict__ g) {
    int b = blockIdx.x;
    int tid = threadIdx.x;
    __shared__ int bounds[2];
    if (tid < 2) {
        int target = b + tid;
        int lo = 0, hi = N_NODES;
        while (lo < hi) {
            int mid = (lo + hi) >> 1;
            if (batch[mid] < target) lo = mid + 1; else hi = mid;
        }
        bounds[tid] = lo;
    }
    __syncthreads();
    int beg = bounds[0], end = bounds[1];
    float s = 0.f;
    for (int r = beg; r < end; r++) s += h[(size_t)r * HDIM + tid];
    g[b * HDIM + tid] = s;
}

// ---------------------------------------------------------------------------
// Fused GEMM: C[M,128] = op(A)[M,128] @ op(B)[128,128] + bias_eff, with
//  PRE_A : A' = relu(A*aCol + bCol)   (BN+relu on A columns, from statsPre)
//  PRE_B : B' = diag(aCol)B, bias_eff = bias + bCol@B   (fold BN left of B)
//  RELU  : C = relu(C)
//  STATS : statsOut += column sums / sumsq of C (post-bias, post-RELU)
// Tile: BM=64, BN=128, BK=64; 256 threads; 4x8 micro-tile (rows ty+16i).
// In-place C==A is safe: all A reads precede all C writes, rows block-disjoint.
// ---------------------------------------------------------------------------
template <bool PRE_A, bool PRE_B, bool RELU, bool STATS>
__global__ __launch_bounds__(256, 3) void gemm_bn(const float* A, const float* __restrict__ B,
                                                  const float* __restrict__ bias, float* C, int M,
                                                  const float* __restrict__ statsPre,
                                                  const float* __restrict__ gammaPre,
                                                  const float* __restrict__ betaPre,
                                                  float invCnt, float* __restrict__ statsOut) {
    __shared__ float At[64][65];    // A transposed: At[k][row], +1 pad (scalar reads)
    __shared__ float Bs[64][128];   // Bs[k][n]
    __shared__ float aPre[128], bPre[128];

    const int tid = threadIdx.x;
    const int tx = tid & 15, ty = tid >> 4;
    const int r0 = blockIdx.x * 64;

    if (PRE_A || PRE_B) {
        if (tid < 128) {
            float m = statsPre[tid] * invCnt;
            float v = statsPre[128 + tid] * invCnt - m * m;
            float a = gammaPre[tid] * rsqrtf(v + BN_EPS);
            aPre[tid] = a;
            bPre[tid] = betaPre[tid] - m * a;
        }
        __syncthreads();
    }

    float acc[4][8];
#pragma unroll
    for (int i = 0; i < 4; i++)
#pragma unroll
        for (int j = 0; j < 8; j++) acc[i][j] = 0.f;

    float biasEff[8];
#pragma unroll
    for (int j = 0; j < 8; j++) biasEff[j] = bias[8 * tx + j];
    if (PRE_B) {
        // bias_eff[n] += sum_k bPre[k] * B[k][n]  (original B, from global/L2)
        for (int k = 0; k < 128; k++) {
            float bb = bPre[k];
            const float* Brow = B + (size_t)k * HDIM + 8 * tx;
#pragma unroll
            for (int j = 0; j < 8; j++) biasEff[j] = fmaf(bb, Brow[j], biasEff[j]);
        }
    }

    for (int kc = 0; kc < 128; kc += 64) {
        // stage A tile (64 rows x 64 k) transposed, optional BN+relu transform
#pragma unroll
        for (int i = 0; i < 4; i++) {
            int f4 = tid + i * 256;
            int row = f4 >> 4;
            int kg = f4 & 15;
            int grow = r0 + row;
            float4 av;
            if (grow < M) av = *(const float4*)(A + (size_t)grow * HDIM + kc + kg * 4);
            else av = make_float4(0.f, 0.f, 0.f, 0.f);
            if (PRE_A) {
                int kb = kc + kg * 4;
                av.x = fmaxf(fmaf(av.x, aPre[kb + 0], bPre[kb + 0]), 0.f);
                av.y = fmaxf(fmaf(av.y, aPre[kb + 1], bPre[kb + 1]), 0.f);
                av.z = fmaxf(fmaf(av.z, aPre[kb + 2], bPre[kb + 2]), 0.f);
                av.w = fmaxf(fmaf(av.w, aPre[kb + 3], bPre[kb + 3]), 0.f);
            }
            At[kg * 4 + 0][row] = av.x;
            At[kg * 4 + 1][row] = av.y;
            At[kg * 4 + 2][row] = av.z;
            At[kg * 4 + 3][row] = av.w;
        }
        // stage B tile (64 k x 128 n), optional column scale
#pragma unroll
        for (int i = 0; i < 8; i++) {
            int f4 = tid + i * 256;
            int krow = f4 >> 5;
            int cg = f4 & 31;
            float4 bv = *(const float4*)(B + (size_t)(kc + krow) * HDIM + cg * 4);
            if (PRE_B) {
                float s = aPre[kc + krow];
                bv.x *= s; bv.y *= s; bv.z *= s; bv.w *= s;
            }
            *(float4*)&Bs[krow][cg * 4] = bv;
        }
        __syncthreads();
#pragma unroll 8
        for (int k = 0; k < 64; k++) {
            float av[4];
            av[0] = At[k][ty];
            av[1] = At[k][ty + 16];
            av[2] = At[k][ty + 32];
            av[3] = At[k][ty + 48];
            const float4 b0 = *(const float4*)&Bs[k][8 * tx];
            const float4 b1 = *(const float4*)&Bs[k][8 * tx + 4];
            float bv[8] = {b0.x, b0.y, b0.z, b0.w, b1.x, b1.y, b1.z, b1.w};
#pragma unroll
            for (int i = 0; i < 4; i++)
#pragma unroll
                for (int j = 0; j < 8; j++) acc[i][j] = fmaf(av[i], bv[j], acc[i][j]);
        }
        __syncthreads();
    }

    float s[8], sq[8];
    if (STATS) {
#pragma unroll
        for (int j = 0; j < 8; j++) { s[j] = 0.f; sq[j] = 0.f; }
    }
#pragma unroll
    for (int i = 0; i < 4; i++) {
        int grow = r0 + ty + 16 * i;
        if (grow < M) {
            float v[8];
#pragma unroll
            for (int j = 0; j < 8; j++) {
                v[j] = acc[i][j] + biasEff[j];
                if (RELU) v[j] = fmaxf(v[j], 0.f);
                if (STATS) { s[j] += v[j]; sq[j] += v[j] * v[j]; }
            }
            float4 o0 = make_float4(v[0], v[1], v[2], v[3]);
            float4 o1 = make_float4(v[4], v[5], v[6], v[7]);
            *(float4*)(C + (size_t)grow * HDIM + 8 * tx) = o0;
            *(float4*)(C + (size_t)grow * HDIM + 8 * tx + 4) = o1;
        }
    }
    if (STATS) {
        float* red = &At[0][0];  // 4160 floats >= 4096; main loop done with At
#pragma unroll
        for (int j = 0; j < 8; j++) {
            red[ty * 128 + 8 * tx + j] = s[j];
            red[2048 + ty * 128 + 8 * tx + j] = sq[j];
        }
        __syncthreads();
        if (tid < 128) {
            float t = 0.f;
#pragma unroll
            for (int u = 0; u < 16; u++) t += red[u * 128 + tid];
            atomicAdd(&statsOut[tid], t);
        } else {
            int col = tid - 128;
            float t = 0.f;
#pragma unroll
            for (int u = 0; u < 16; u++) t += red[2048 + u * 128 + col];
            atomicAdd(&statsOut[128 + col], t);
        }
    }
}

// ---------------------------------------------------------------------------
// Head: logits = BN(g2)@W_cls + b_cls (BN folded), then log_softmax.
// ---------------------------------------------------------------------------
__global__ __launch_bounds__(256) void head_kernel(const float* __restrict__ g2,
                                                   const float* __restrict__ stats,
                                                   const float* __restrict__ gamma,
                                                   const float* __restrict__ beta,
                                                   const float* __restrict__ Wc,
                                                   const float* __restrict__ bc,
                                                   float* __restrict__ out, float invCnt) {
    __shared__ float Wf[HDIM * NCLS];
    __shared__ float bf[NCLS];
    __shared__ float aP[HDIM], bP[HDIM];
    const int tid = threadIdx.x;
    if (tid < HDIM) {
        float m = stats[tid] * invCnt;
        float v = stats[HDIM + tid] * invCnt - m * m;
        float a = gamma[tid] * rsqrtf(v + BN_EPS);
        aP[tid] = a;
        bP[tid] = beta[tid] - m * a;
    }
    __syncthreads();
    for (int idx = tid; idx < HDIM * NCLS; idx += 256) {
        int k = idx / NCLS;
        Wf[idx] = aP[k] * Wc[idx];
    }
    if (tid < NCLS) {
        float sv = bc[tid];
        for (int k = 0; k < HDIM; k++) sv = fmaf(bP[k], Wc[k * NCLS + tid], sv);
        bf[tid] = sv;
    }
    __syncthreads();
    int row = blockIdx.x * 256 + tid;
    if (row >= NGRAPH) return;
    float l[NCLS];
#pragma unroll
    for (int c = 0; c < NCLS; c++) l[c] = bf[c];
    for (int k = 0; k < HDIM; k++) {
        float gv = g2[row * HDIM + k];
#pragma unroll
        for (int c = 0; c < NCLS; c++) l[c] = fmaf(gv, Wf[k * NCLS + c], l[c]);
    }
    float mx = l[0];
#pragma unroll
    for (int c = 1; c < NCLS; c++) mx = fmaxf(mx, l[c]);
    float se = 0.f;
#pragma unroll
    for (int c = 0; c < NCLS; c++) se += expf(l[c] - mx);
    float lse = mx + logf(se);
#pragma unroll
    for (int c = 0; c < NCLS; c++) out[row * NCLS + c] = l[c] - lse;
}

// ---------------------------------------------------------------------------
extern "C" void kernel_launch(void* const* d_in, const int* in_sizes, int n_in,
                              void* d_out, int out_size, void* d_ws, size_t ws_size,
                              hipStream_t stream) {
    const float* x          = (const float*)d_in[0];
    const int*   ei         = (const int*)d_in[1];
    const int*   batch      = (const int*)d_in[2];
    const float* gamma_feat = (const float*)d_in[3];
    const float* beta_feat  = (const float*)d_in[4];
    const float* W_feat     = (const float*)d_in[5];
    const float* b_feat     = (const float*)d_in[6];
    const float* gin_W1     = (const float*)d_in[7];
    const float* gin_b1     = (const float*)d_in[8];
    const float* gin_gamma  = (const float*)d_in[9];
    const float* gin_beta   = (const float*)d_in[10];
    const float* gin_W2     = (const float*)d_in[11];
    const float* gin_b2     = (const float*)d_in[12];
    const float* gamma_fc   = (const float*)d_in[13];
    const float* beta_fc    = (const float*)d_in[14];
    const float* W_fc       = (const float*)d_in[15];
    const float* b_fc       = (const float*)d_in[16];
    const float* gamma_h    = (const float*)d_in[17];
    const float* beta_h     = (const float*)d_in[18];
    const float* W_cls      = (const float*)d_in[19];
    const float* b_cls      = (const float*)d_in[20];
    float* out = (float*)d_out;

    float* ws = (float*)d_ws;
    size_t off = 0;
    float* h  = ws + off; off += (size_t)N_NODES * HDIM;
    float* zy = ws + off; off += (size_t)N_NODES * HDIM;   // z and y alias (in-place gemm)
    float* g2 = ws + off; off += NGRAPH * HDIM;
    float* g  = ws + off; off += NGRAPH * HDIM;            // fully written by segsum2
    size_t zstart = off;                                    // ---- zeroed region ----
    float* stats = ws + off; off += 256 * 6;
    int* counts = (int*)(ws + off); off += N_NODES;
    size_t zbytes = (off - zstart) * sizeof(float);         // ---- end zeroed ----
    int* offsets   = (int*)(ws + off); off += N_NODES + 1;
    int* cursor    = (int*)(ws + off); off += N_NODES;
    int* csr       = (int*)(ws + off); off += N_EDGES;
    int* partial   = (int*)(ws + off); off += N_NODES;
    int* blockSums = (int*)(ws + off); off += 256;
    int* blockBase = (int*)(ws + off); off += 256;

    float* statsX  = stats;
    float* statsY0 = stats + 256;
    float* statsY1 = stats + 512;
    float* statsY2 = stats + 768;
    float* statsYa[3] = {statsY0, statsY1, statsY2};
    float* statsG  = stats + 1024;
    float* statsG2 = stats + 1280;

    hipMemsetAsync(stats, 0, zbytes, stream);

    const float invN = 1.f / (float)N_NODES;
    const float invG = 1.f / (float)NGRAPH;
    const int gblocks = (N_NODES + 63) / 64;         // 782
    const int eblocks = (N_EDGES + 255) / 256;       // 2344
    const int nwaves  = (N_NODES * 64 + 255) / 256;  // 12500

    // BN(x) stats + CSR build
    colstats_kernel<<<256, 256, 0, stream>>>(x, N_NODES, statsX);
    hist_kernel<<<eblocks, 256, 0, stream>>>(ei, counts);
    scan1_kernel<<<SCAN_BLOCKS, 256, 0, stream>>>(counts, partial, blockSums);
    scan2_kernel<<<1, 256, 0, stream>>>(blockSums, blockBase);
    scan3_kernel<<<SCAN_BLOCKS, 256, 0, stream>>>(partial, blockBase, offsets, cursor);
    fill_kernel<<<eblocks, 256, 0, stream>>>(ei, cursor, csr);

    // h = relu(BN(x) @ W_feat + b_feat)   [BN folded into B]
    gemm_bn<false, true, true, false><<<gblocks, 256, 0, stream>>>(
        x, W_feat, b_feat, h, N_NODES, statsX, gamma_feat, beta_feat, invN, nullptr);

    for (int i = 0; i < 3; i++) {
        // z = h + sum_neighbors h
        agg_kernel<<<nwaves, 256, 0, stream>>>(h, offsets, csr, zy);
        // y = z @ W1 + b1  (in-place, + column stats of y)
        gemm_bn<false, false, false, true><<<gblocks, 256, 0, stream>>>(
            zy, gin_W1 + i * HDIM * HDIM, gin_b1 + i * HDIM, zy, N_NODES,
            nullptr, nullptr, nullptr, invN, statsYa[i]);
        // h = relu( relu(BN(y)) @ W2 + b2 )  [BN+relu applied to A at staging]
        gemm_bn<true, false, true, false><<<gblocks, 256, 0, stream>>>(
            zy, gin_W2 + i * HDIM * HDIM, gin_b2 + i * HDIM, h, N_NODES,
            statsYa[i], gin_gamma + i * HDIM, gin_beta + i * HDIM, invN, nullptr);
    }

    // g = segment_sum(h, batch)  (sorted batch -> direct per-graph reduce)
    segsum2_kernel<<<NGRAPH, 128, 0, stream>>>(h, batch, g);
    colstats_kernel<<<8, 256, 0, stream>>>(g, NGRAPH, statsG);
    // g2 = relu(BN(g) @ W_fc + b_fc) + stats of g2
    gemm_bn<false, true, true, true><<<(NGRAPH + 63) / 64, 256, 0, stream>>>(
        g, W_fc, b_fc, g2, NGRAPH, statsG, gamma_fc, beta_fc, invG, statsG2);
    // logits = BN(g2) @ W_cls + b_cls -> log_softmax
    head_kernel<<<2, 256, 0, stream>>>(g2, statsG2, gamma_h, beta_h, W_cls, b_cls, out, invG);
}

// Round 7
// 709.344 us; speedup vs baseline: 1.2430x; 1.0395x over previous
//
#include <hip/hip_runtime.h>
#include <math.h>

#define N_NODES 50000
#define N_EDGES 600000
#define HDIM 128
#define NCLS 10
#define NGRAPH 500
#define BN_EPS 1e-5f
#define SCAN_BLOCKS 196  // ceil(N_NODES/256)

typedef short bf16x8 __attribute__((ext_vector_type(8)));
typedef float f32x4 __attribute__((ext_vector_type(4)));

// ---------------------------------------------------------------------------
// Column stats: stats[0..127] += column sums, stats[128..255] += column sumsq
// ---------------------------------------------------------------------------
__global__ void colstats_kernel(const float* __restrict__ X, int M, float* __restrict__ stats) {
    int col = threadIdx.x & 127;
    int sub = threadIdx.x >> 7;
    float s = 0.f, sq = 0.f;
    for (int r = blockIdx.x * 2 + sub; r < M; r += gridDim.x * 2) {
        float v = X[(size_t)r * HDIM + col];
        s += v; sq += v * v;
    }
    atomicAdd(&stats[col], s);
    atomicAdd(&stats[HDIM + col], sq);
}

// ---------------------------------------------------------------------------
// CSR build: histogram over dst, 3-level multiblock exclusive scan, scatter
// ---------------------------------------------------------------------------
__global__ void hist_kernel(const int* __restrict__ ei, int* __restrict__ counts) {
    int e = blockIdx.x * 256 + threadIdx.x;
    if (e < N_EDGES) atomicAdd(&counts[ei[N_EDGES + e]], 1);
}

__global__ __launch_bounds__(256) void scan1_kernel(const int* __restrict__ counts,
                                                    int* __restrict__ partial,
                                                    int* __restrict__ blockSums) {
    __shared__ int tmp[256];
    int tid = threadIdx.x;
    int i = blockIdx.x * 256 + tid;
    int v = (i < N_NODES) ? counts[i] : 0;
    tmp[tid] = v;
    __syncthreads();
#pragma unroll
    for (int off = 1; off < 256; off <<= 1) {
        int t = (tid >= off) ? tmp[tid - off] : 0;
        __syncthreads();
        tmp[tid] += t;
        __syncthreads();
    }
    if (i < N_NODES) partial[i] = tmp[tid] - v;
    if (tid == 255) blockSums[blockIdx.x] = tmp[255];
}

__global__ __launch_bounds__(256) void scan2_kernel(const int* __restrict__ blockSums,
                                                    int* __restrict__ blockBase) {
    __shared__ int tmp[256];
    int tid = threadIdx.x;
    int v = (tid < SCAN_BLOCKS) ? blockSums[tid] : 0;
    tmp[tid] = v;
    __syncthreads();
#pragma unroll
    for (int off = 1; off < 256; off <<= 1) {
        int t = (tid >= off) ? tmp[tid - off] : 0;
        __syncthreads();
        tmp[tid] += t;
        __syncthreads();
    }
    if (tid < SCAN_BLOCKS) blockBase[tid] = tmp[tid] - v;
}

__global__ __launch_bounds__(256) void scan3_kernel(const int* __restrict__ partial,
                                                    const int* __restrict__ blockBase,
                                                    int* __restrict__ offsets,
                                                    int* __restrict__ cursor) {
    int i = blockIdx.x * 256 + threadIdx.x;
    if (i < N_NODES) {
        int o = partial[i] + blockBase[blockIdx.x];
        offsets[i] = o;
        cursor[i] = o;
    }
    if (i == 0) offsets[N_NODES] = N_EDGES;
}

__global__ void fill_kernel(const int* __restrict__ ei, int* __restrict__ cursor, int* __restrict__ csr) {
    int e = blockIdx.x * 256 + threadIdx.x;
    if (e < N_EDGES) {
        int d = ei[N_EDGES + e];
        int pos = atomicAdd(&cursor[d], 1);
        csr[pos] = ei[e];
    }
}

// ---------------------------------------------------------------------------
// GIN aggregation (unchanged): z[n] = h[n] + sum_{src->n} h[src]
// ---------------------------------------------------------------------------
__global__ __launch_bounds__(256) void agg_kernel(const float* __restrict__ h,
                                                  const int* __restrict__ offsets,
                                                  const int* __restrict__ csr,
                                                  float* __restrict__ z) {
    int node = (blockIdx.x * 256 + threadIdx.x) >> 6;
    int lane = threadIdx.x & 63;
    if (node >= N_NODES) return;
    int c0 = lane * 2;
    int beg = offsets[node], end = offsets[node + 1];
    const float2 self = *(const float2*)&h[(size_t)node * HDIM + c0];
    float ax = self.x, ay = self.y;
    for (int j = beg; j < end; j += 64) {
        int cnt = min(64, end - j);
        int sl = (j + lane < end) ? csr[j + lane] : 0;
        int t = 0;
        for (; t + 4 <= cnt; t += 4) {
            int s0 = __shfl(sl, t, 64);
            int s1 = __shfl(sl, t + 1, 64);
            int s2 = __shfl(sl, t + 2, 64);
            int s3 = __shfl(sl, t + 3, 64);
            float2 v0 = *(const float2*)&h[(size_t)s0 * HDIM + c0];
            float2 v1 = *(const float2*)&h[(size_t)s1 * HDIM + c0];
            float2 v2 = *(const float2*)&h[(size_t)s2 * HDIM + c0];
            float2 v3 = *(const float2*)&h[(size_t)s3 * HDIM + c0];
            ax += v0.x + v1.x + v2.x + v3.x;
            ay += v0.y + v1.y + v2.y + v3.y;
        }
        for (; t < cnt; t++) {
            int s = __shfl(sl, t, 64);
            float2 hv = *(const float2*)&h[(size_t)s * HDIM + c0];
            ax += hv.x; ay += hv.y;
        }
    }
    float2 o; o.x = ax; o.y = ay;
    *(float2*)&z[(size_t)node * HDIM + c0] = o;
}

// ---------------------------------------------------------------------------
// segment_sum (unchanged): sorted batch -> per-graph direct reduce
// ---------------------------------------------------------------------------
__global__ __launch_bounds__(128) void segsum2_kernel(const float* __restrict__ h,
                                                      const int* __restrict__ batch,
                                                      float* __restrict__ g) {
    int b = blockIdx.x;
    int tid = threadIdx.x;
    __shared__ int bounds[2];
    if (tid < 2) {
        int target = b + tid;
        int lo = 0, hi = N_NODES;
        while (lo < hi) {
            int mid = (lo + hi) >> 1;
            if (batch[mid] < target) lo = mid + 1; else hi = mid;
        }
        bounds[tid] = lo;
    }
    __syncthreads();
    int beg = bounds[0], end = bounds[1];
    float s = 0.f;
    for (int r = beg; r < end; r++) s += h[(size_t)r * HDIM + tid];
    g[b * HDIM + tid] = s;
}

// ---------------------------------------------------------------------------
// Weight prep: transpose W[k][n] -> Wt[n][k] and Dekker-split to bf16 hi/lo.
// prep_w: 6 GIN weight matrices (blocks 0-2: W1 layers, 3-5: W2 layers).
// prep_feat: W_feat with BN(x) folded (W' = diag(a)W, biasF = b + bPre@W).
// ---------------------------------------------------------------------------
__device__ inline void dekker_split(float v, unsigned short& hi, unsigned short& lo) {
    unsigned u = __float_as_uint(v);
    hi = (unsigned short)(u >> 16);
    float flo = v - __uint_as_float(u & 0xffff0000u);
    lo = (unsigned short)(__float_as_uint(flo) >> 16);
}

__global__ __launch_bounds__(256) void prep_w(const float* __restrict__ W1,
                                              const float* __restrict__ W2,
                                              unsigned short* __restrict__ wh,
                                              unsigned short* __restrict__ wl) {
    int m = blockIdx.x;  // 0..5
    const float* src = (m < 3) ? (W1 + m * HDIM * HDIM) : (W2 + (m - 3) * HDIM * HDIM);
    unsigned short* dh = wh + m * HDIM * HDIM;
    unsigned short* dl = wl + m * HDIM * HDIM;
    for (int i = threadIdx.x; i < HDIM * HDIM; i += 256) {
        int n = i >> 7, k = i & 127;
        float v = src[k * HDIM + n];
        unsigned short h16, l16;
        dekker_split(v, h16, l16);
        dh[i] = h16; dl[i] = l16;
    }
}

__global__ __launch_bounds__(256) void prep_feat(const float* __restrict__ W,
                                                 const float* __restrict__ bfeat,
                                                 const float* __restrict__ stats,
                                                 const float* __restrict__ gamma,
                                                 const float* __restrict__ beta,
                                                 float invCnt,
                                                 unsigned short* __restrict__ dh,
                                                 unsigned short* __restrict__ dl,
                                                 float* __restrict__ biasF) {
    __shared__ float aP[HDIM], bP[HDIM];
    int tid = threadIdx.x;
    if (tid < HDIM) {
        float m = stats[tid] * invCnt;
        float v = stats[HDIM + tid] * invCnt - m * m;
        float a = gamma[tid] * rsqrtf(v + BN_EPS);
        aP[tid] = a;
        bP[tid] = beta[tid] - m * a;
    }
    __syncthreads();
    for (int i = tid; i < HDIM * HDIM; i += 256) {
        int n = i >> 7, k = i & 127;
        float v = aP[k] * W[k * HDIM + n];
        unsigned short h16, l16;
        dekker_split(v, h16, l16);
        dh[i] = h16; dl[i] = l16;
    }
    if (tid < HDIM) {
        float acc = bfeat[tid];
        for (int k = 0; k < HDIM; k++) acc = fmaf(bP[k], W[k * HDIM + tid], acc);
        biasF[tid] = acc;
    }
}

// ---------------------------------------------------------------------------
// MFMA GEMM: C[M,128] = op(A)[M,128] @ B[128,128] + bias, via bf16 Dekker
// split (3-term: AhBh + AlBh + AhBl, fp32 accumulate).
// MODE 0 (feat): A fp32 plain, RELU out.            (BN folded in prepped B)
// MODE 1 (gin1): A fp32 plain, no relu, STATS out, in-place safe (per-wave band).
// MODE 2 (gin2): A fp32 + in-reg BN+relu (PRE_A from statsPre), RELU out.
// Layout: 256 thr = 4 waves; wave w owns rows [bid*128+w*32, +32) x all 128 cols.
// Per wave: 2 row-tiles x 8 col-tiles of 16x16, K in 4 steps of 32.
// mfma_f32_16x16x32_bf16 frags: A lane row=l&15, k=(l>>4)*8+j (8 consecutive);
// B from Wt[n][k]: lane col=l&15, same k slice; C/D: col=l&15, row=(l>>4)*4+reg.
// NO LDS, NO barriers: A frag loads are wave-coalesced from global (16 rows x
// 64B), B streams from L2-hot prepped weights.
// ---------------------------------------------------------------------------
template <int MODE>
__global__ __launch_bounds__(256, 2) void mfma_gemm(const float* __restrict__ A,
                                                    const unsigned short* __restrict__ Bh,
                                                    const unsigned short* __restrict__ Bl,
                                                    const float* __restrict__ bias,
                                                    float* __restrict__ C, int M,
                                                    const float* __restrict__ statsPre,
                                                    const float* __restrict__ gammaPre,
                                                    const float* __restrict__ betaPre,
                                                    float invCnt,
                                                    float* __restrict__ statsOut) {
    const int tid = threadIdx.x;
    const int w = tid >> 6, l = tid & 63;
    const int q = l >> 4, c16 = l & 15;
    const int rb = blockIdx.x * 128 + w * 32;

    int rowA[2];
#pragma unroll
    for (int rt = 0; rt < 2; rt++) rowA[rt] = min(rb + rt * 16 + c16, M - 1);

    float bs[8];
#pragma unroll
    for (int c = 0; c < 8; c++) bs[c] = bias[c * 16 + c16];

    f32x4 acc[2][8];
#pragma unroll
    for (int rt = 0; rt < 2; rt++)
#pragma unroll
        for (int c = 0; c < 8; c++) acc[rt][c] = (f32x4){0.f, 0.f, 0.f, 0.f};

#pragma unroll
    for (int s = 0; s < 4; s++) {
        const int k0 = s * 32 + q * 8;
        float aK[8], bK[8];
        if (MODE == 2) {
#pragma unroll
            for (int j = 0; j < 8; j++) {
                int k = k0 + j;
                float m = statsPre[k] * invCnt;
                float var = statsPre[HDIM + k] * invCnt - m * m;
                float a = gammaPre[k] * rsqrtf(var + BN_EPS);
                aK[j] = a;
                bK[j] = betaPre[k] - m * a;
            }
        }
        bf16x8 ah[2], al[2];
#pragma unroll
        for (int rt = 0; rt < 2; rt++) {
            const float* ap = A + (size_t)rowA[rt] * HDIM + k0;
            float4 v0 = *(const float4*)ap;
            float4 v1 = *(const float4*)(ap + 4);
            float vv[8] = {v0.x, v0.y, v0.z, v0.w, v1.x, v1.y, v1.z, v1.w};
#pragma unroll
            for (int j = 0; j < 8; j++) {
                float v = vv[j];
                if (MODE == 2) v = fmaxf(fmaf(v, aK[j], bK[j]), 0.f);
                unsigned u = __float_as_uint(v);
                ah[rt][j] = (short)(u >> 16);
                float flo = v - __uint_as_float(u & 0xffff0000u);
                al[rt][j] = (short)(__float_as_uint(flo) >> 16);
            }
        }
#pragma unroll
        for (int c = 0; c < 8; c++) {
            const size_t bo = (size_t)(c * 16 + c16) * HDIM + k0;
            bf16x8 bh = *(const bf16x8*)(Bh + bo);
            bf16x8 bl = *(const bf16x8*)(Bl + bo);
#pragma unroll
            for (int rt = 0; rt < 2; rt++) {
                acc[rt][c] = __builtin_amdgcn_mfma_f32_16x16x32_bf16(ah[rt], bh, acc[rt][c], 0, 0, 0);
                acc[rt][c] = __builtin_amdgcn_mfma_f32_16x16x32_bf16(al[rt], bh, acc[rt][c], 0, 0, 0);
                acc[rt][c] = __builtin_amdgcn_mfma_f32_16x16x32_bf16(ah[rt], bl, acc[rt][c], 0, 0, 0);
            }
        }
    }

    float ssum[8], ssq[8];
    if (MODE == 1) {
#pragma unroll
        for (int c = 0; c < 8; c++) { ssum[c] = 0.f; ssq[c] = 0.f; }
    }
#pragma unroll
    for (int rt = 0; rt < 2; rt++) {
#pragma unroll
        for (int reg = 0; reg < 4; reg++) {
            int row = rb + rt * 16 + q * 4 + reg;
            if (row < M) {
                float* cp = C + (size_t)row * HDIM + c16;
#pragma unroll
                for (int c = 0; c < 8; c++) {
                    float v = acc[rt][c][reg] + bs[c];
                    if (MODE != 1) v = fmaxf(v, 0.f);
                    cp[c * 16] = v;
                    if (MODE == 1) { ssum[c] += v; ssq[c] += v * v; }
                }
            }
        }
    }
    if (MODE == 1) {
#pragma unroll
        for (int c = 0; c < 8; c++) {
            float s2 = ssum[c] + __shfl_xor(ssum[c], 16, 64);
            float s4 = s2 + __shfl_xor(s2, 32, 64);
            float t2 = ssq[c] + __shfl_xor(ssq[c], 16, 64);
            float t4 = t2 + __shfl_xor(t2, 32, 64);
            if (q == 0) {
                atomicAdd(&statsOut[c * 16 + c16], s4);
                atomicAdd(&statsOut[HDIM + c * 16 + c16], t4);
            }
        }
    }
}

// ---------------------------------------------------------------------------
// Small fp32 GEMM (kept for the 500-row FC block): see R2 notes.
// ---------------------------------------------------------------------------
template <bool PRE_A, bool PRE_B, bool RELU, bool STATS>
__global__ __launch_bounds__(256, 3) void gemm_bn(const float* A, const float* __restrict__ B,
                                                  const float* __restrict__ bias, float* C, int M,
                                                  const float* __restrict__ statsPre,
                                                  const float* __restrict__ gammaPre,
                                                  const float* __restrict__ betaPre,
                                                  float invCnt, float* __restrict__ statsOut) {
    __shared__ float At[64][65];
    __shared__ float Bs[64][128];
    __shared__ float aPre[128], bPre[128];

    const int tid = threadIdx.x;
    const int tx = tid & 15, ty = tid >> 4;
    const int r0 = blockIdx.x * 64;

    if (PRE_A || PRE_B) {
        if (tid < 128) {
            float m = statsPre[tid] * invCnt;
            float v = statsPre[128 + tid] * invCnt - m * m;
            float a = gammaPre[tid] * rsqrtf(v + BN_EPS);
            aPre[tid] = a;
            bPre[tid] = betaPre[tid] - m * a;
        }
        __syncthreads();
    }

    float acc[4][8];
#pragma unroll
    for (int i = 0; i < 4; i++)
#pragma unroll
        for (int j = 0; j < 8; j++) acc[i][j] = 0.f;

    float biasEff[8];
#pragma unroll
    for (int j = 0; j < 8; j++) biasEff[j] = bias[8 * tx + j];
    if (PRE_B) {
        for (int k = 0; k < 128; k++) {
            float bb = bPre[k];
            const float* Brow = B + (size_t)k * HDIM + 8 * tx;
#pragma unroll
            for (int j = 0; j < 8; j++) biasEff[j] = fmaf(bb, Brow[j], biasEff[j]);
        }
    }

    for (int kc = 0; kc < 128; kc += 64) {
#pragma unroll
        for (int i = 0; i < 4; i++) {
            int f4 = tid + i * 256;
            int row = f4 >> 4;
            int kg = f4 & 15;
            int grow = r0 + row;
            float4 av;
            if (grow < M) av = *(const float4*)(A + (size_t)grow * HDIM + kc + kg * 4);
            else av = make_float4(0.f, 0.f, 0.f, 0.f);
            if (PRE_A) {
                int kb = kc + kg * 4;
                av.x = fmaxf(fmaf(av.x, aPre[kb + 0], bPre[kb + 0]), 0.f);
                av.y = fmaxf(fmaf(av.y, aPre[kb + 1], bPre[kb + 1]), 0.f);
                av.z = fmaxf(fmaf(av.z, aPre[kb + 2], bPre[kb + 2]), 0.f);
                av.w = fmaxf(fmaf(av.w, aPre[kb + 3], bPre[kb + 3]), 0.f);
            }
            At[kg * 4 + 0][row] = av.x;
            At[kg * 4 + 1][row] = av.y;
            At[kg * 4 + 2][row] = av.z;
            At[kg * 4 + 3][row] = av.w;
        }
#pragma unroll
        for (int i = 0; i < 8; i++) {
            int f4 = tid + i * 256;
            int krow = f4 >> 5;
            int cg = f4 & 31;
            float4 bv = *(const float4*)(B + (size_t)(kc + krow) * HDIM + cg * 4);
            if (PRE_B) {
                float s = aPre[kc + krow];
                bv.x *= s; bv.y *= s; bv.z *= s; bv.w *= s;
            }
            *(float4*)&Bs[krow][cg * 4] = bv;
        }
        __syncthreads();
#pragma unroll 8
        for (int k = 0; k < 64; k++) {
            float av[4];
            av[0] = At[k][ty];
            av[1] = At[k][ty + 16];
            av[2] = At[k][ty + 32];
            av[3] = At[k][ty + 48];
            const float4 b0 = *(const float4*)&Bs[k][8 * tx];
            const float4 b1 = *(const float4*)&Bs[k][8 * tx + 4];
            float bv[8] = {b0.x, b0.y, b0.z, b0.w, b1.x, b1.y, b1.z, b1.w};
#pragma unroll
            for (int i = 0; i < 4; i++)
#pragma unroll
                for (int j = 0; j < 8; j++) acc[i][j] = fmaf(av[i], bv[j], acc[i][j]);
        }
        __syncthreads();
    }

    float s[8], sq[8];
    if (STATS) {
#pragma unroll
        for (int j = 0; j < 8; j++) { s[j] = 0.f; sq[j] = 0.f; }
    }
#pragma unroll
    for (int i = 0; i < 4; i++) {
        int grow = r0 + ty + 16 * i;
        if (grow < M) {
            float v[8];
#pragma unroll
            for (int j = 0; j < 8; j++) {
                v[j] = acc[i][j] + biasEff[j];
                if (RELU) v[j] = fmaxf(v[j], 0.f);
                if (STATS) { s[j] += v[j]; sq[j] += v[j] * v[j]; }
            }
            float4 o0 = make_float4(v[0], v[1], v[2], v[3]);
            float4 o1 = make_float4(v[4], v[5], v[6], v[7]);
            *(float4*)(C + (size_t)grow * HDIM + 8 * tx) = o0;
            *(float4*)(C + (size_t)grow * HDIM + 8 * tx + 4) = o1;
        }
    }
    if (STATS) {
        float* red = &At[0][0];
#pragma unroll
        for (int j = 0; j < 8; j++) {
            red[ty * 128 + 8 * tx + j] = s[j];
            red[2048 + ty * 128 + 8 * tx + j] = sq[j];
        }
        __syncthreads();
        if (tid < 128) {
            float t = 0.f;
#pragma unroll
            for (int u = 0; u < 16; u++) t += red[u * 128 + tid];
            atomicAdd(&statsOut[tid], t);
        } else {
            int col = tid - 128;
            float t = 0.f;
#pragma unroll
            for (int u = 0; u < 16; u++) t += red[2048 + u * 128 + col];
            atomicAdd(&statsOut[128 + col], t);
        }
    }
}

// ---------------------------------------------------------------------------
// Head: logits = BN(g2)@W_cls + b_cls (BN folded), then log_softmax.
// ---------------------------------------------------------------------------
__global__ __launch_bounds__(256) void head_kernel(const float* __restrict__ g2,
                                                   const float* __restrict__ stats,
                                                   const float* __restrict__ gamma,
                                                   const float* __restrict__ beta,
                                                   const float* __restrict__ Wc,
                                                   const float* __restrict__ bc,
                                                   float* __restrict__ out, float invCnt) {
    __shared__ float Wf[HDIM * NCLS];
    __shared__ float bf[NCLS];
    __shared__ float aP[HDIM], bP[HDIM];
    const int tid = threadIdx.x;
    if (tid < HDIM) {
        float m = stats[tid] * invCnt;
        float v = stats[HDIM + tid] * invCnt - m * m;
        float a = gamma[tid] * rsqrtf(v + BN_EPS);
        aP[tid] = a;
        bP[tid] = beta[tid] - m * a;
    }
    __syncthreads();
    for (int idx = tid; idx < HDIM * NCLS; idx += 256) {
        int k = idx / NCLS;
        Wf[idx] = aP[k] * Wc[idx];
    }
    if (tid < NCLS) {
        float sv = bc[tid];
        for (int k = 0; k < HDIM; k++) sv = fmaf(bP[k], Wc[k * NCLS + tid], sv);
        bf[tid] = sv;
    }
    __syncthreads();
    int row = blockIdx.x * 256 + tid;
    if (row >= NGRAPH) return;
    float l[NCLS];
#pragma unroll
    for (int c = 0; c < NCLS; c++) l[c] = bf[c];
    for (int k = 0; k < HDIM; k++) {
        float gv = g2[row * HDIM + k];
#pragma unroll
        for (int c = 0; c < NCLS; c++) l[c] = fmaf(gv, Wf[k * NCLS + c], l[c]);
    }
    float mx = l[0];
#pragma unroll
    for (int c = 1; c < NCLS; c++) mx = fmaxf(mx, l[c]);
    float se = 0.f;
#pragma unroll
    for (int c = 0; c < NCLS; c++) se += expf(l[c] - mx);
    float lse = mx + logf(se);
#pragma unroll
    for (int c = 0; c < NCLS; c++) out[row * NCLS + c] = l[c] - lse;
}

// ---------------------------------------------------------------------------
extern "C" void kernel_launch(void* const* d_in, const int* in_sizes, int n_in,
                              void* d_out, int out_size, void* d_ws, size_t ws_size,
                              hipStream_t stream) {
    const float* x          = (const float*)d_in[0];
    const int*   ei         = (const int*)d_in[1];
    const int*   batch      = (const int*)d_in[2];
    const float* gamma_feat = (const float*)d_in[3];
    const float* beta_feat  = (const float*)d_in[4];
    const float* W_feat     = (const float*)d_in[5];
    const float* b_feat     = (const float*)d_in[6];
    const float* gin_W1     = (const float*)d_in[7];
    const float* gin_b1     = (const float*)d_in[8];
    const float* gin_gamma  = (const float*)d_in[9];
    const float* gin_beta   = (const float*)d_in[10];
    const float* gin_W2     = (const float*)d_in[11];
    const float* gin_b2     = (const float*)d_in[12];
    const float* gamma_fc   = (const float*)d_in[13];
    const float* beta_fc    = (const float*)d_in[14];
    const float* W_fc       = (const float*)d_in[15];
    const float* b_fc       = (const float*)d_in[16];
    const float* gamma_h    = (const float*)d_in[17];
    const float* beta_h     = (const float*)d_in[18];
    const float* W_cls      = (const float*)d_in[19];
    const float* b_cls      = (const float*)d_in[20];
    float* out = (float*)d_out;

    float* ws = (float*)d_ws;
    size_t off = 0;
    float* h  = ws + off; off += (size_t)N_NODES * HDIM;
    float* zy = ws + off; off += (size_t)N_NODES * HDIM;   // z and y alias (per-wave-band in-place gemm)
    float* g2 = ws + off; off += NGRAPH * HDIM;
    float* g  = ws + off; off += NGRAPH * HDIM;            // fully written by segsum2
    size_t zstart = off;                                    // ---- zeroed region ----
    float* stats = ws + off; off += 256 * 6;
    int* counts = (int*)(ws + off); off += N_NODES;
    size_t zbytes = (off - zstart) * sizeof(float);         // ---- end zeroed ----
    int* offsets   = (int*)(ws + off); off += N_NODES + 1;
    int* cursor    = (int*)(ws + off); off += N_NODES;
    int* csr       = (int*)(ws + off); off += N_EDGES;
    int* partial   = (int*)(ws + off); off += N_NODES;
    int* blockSums = (int*)(ws + off); off += 256;
    int* blockBase = (int*)(ws + off); off += 256;
    off = (off + 3) & ~(size_t)3;                           // 16B-align weight arrays
    unsigned short* wt_hi = (unsigned short*)(ws + off); off += 7 * HDIM * HDIM / 2;
    unsigned short* wt_lo = (unsigned short*)(ws + off); off += 7 * HDIM * HDIM / 2;
    float* biasF = ws + off; off += HDIM;

    float* statsX  = stats;
    float* statsYa[3] = {stats + 256, stats + 512, stats + 768};
    float* statsG  = stats + 1024;
    float* statsG2 = stats + 1280;

    hipMemsetAsync(stats, 0, zbytes, stream);

    const float invN = 1.f / (float)N_NODES;
    const float invG = 1.f / (float)NGRAPH;
    const int eblocks = (N_EDGES + 255) / 256;        // 2344
    const int nwaves  = (N_NODES * 64 + 255) / 256;   // 12500
    const int mblocks = (N_NODES + 127) / 128;        // 391

    // GIN weight prep (no deps) + BN(x) stats + CSR build
    prep_w<<<6, 256, 0, stream>>>(gin_W1, gin_W2, wt_hi, wt_lo);
    colstats_kernel<<<256, 256, 0, stream>>>(x, N_NODES, statsX);
    hist_kernel<<<eblocks, 256, 0, stream>>>(ei, counts);
    scan1_kernel<<<SCAN_BLOCKS, 256, 0, stream>>>(counts, partial, blockSums);
    scan2_kernel<<<1, 256, 0, stream>>>(blockSums, blockBase);
    scan3_kernel<<<SCAN_BLOCKS, 256, 0, stream>>>(partial, blockBase, offsets, cursor);
    fill_kernel<<<eblocks, 256, 0, stream>>>(ei, cursor, csr);
    prep_feat<<<1, 256, 0, stream>>>(W_feat, b_feat, statsX, gamma_feat, beta_feat, invN,
                                     wt_hi + 6 * HDIM * HDIM, wt_lo + 6 * HDIM * HDIM, biasF);

    // h = relu(BN(x) @ W_feat + b_feat)   [BN folded into prepped B]
    mfma_gemm<0><<<mblocks, 256, 0, stream>>>(
        x, wt_hi + 6 * HDIM * HDIM, wt_lo + 6 * HDIM * HDIM, biasF, h, N_NODES,
        nullptr, nullptr, nullptr, invN, nullptr);

    for (int i = 0; i < 3; i++) {
        // z = h + sum_neighbors h
        agg_kernel<<<nwaves, 256, 0, stream>>>(h, offsets, csr, zy);
        // y = z @ W1 + b1   (in-place, + column stats of y)
        mfma_gemm<1><<<mblocks, 256, 0, stream>>>(
            zy, wt_hi + i * HDIM * HDIM, wt_lo + i * HDIM * HDIM, gin_b1 + i * HDIM,
            zy, N_NODES, nullptr, nullptr, nullptr, invN, statsYa[i]);
        // h = relu( relu(BN(y)) @ W2 + b2 )   [BN+relu in-register on A frags]
        mfma_gemm<2><<<mblocks, 256, 0, stream>>>(
            zy, wt_hi + (3 + i) * HDIM * HDIM, wt_lo + (3 + i) * HDIM * HDIM, gin_b2 + i * HDIM,
            h, N_NODES, statsYa[i], gin_gamma + i * HDIM, gin_beta + i * HDIM, invN, nullptr);
    }

    // g = segment_sum(h, batch)  (sorted batch -> direct per-graph reduce)
    segsum2_kernel<<<NGRAPH, 128, 0, stream>>>(h, batch, g);
    colstats_kernel<<<8, 256, 0, stream>>>(g, NGRAPH, statsG);
    // g2 = relu(BN(g) @ W_fc + b_fc) + stats of g2
    gemm_bn<false, true, true, true><<<(NGRAPH + 63) / 64, 256, 0, stream>>>(
        g, W_fc, b_fc, g2, NGRAPH, statsG, gamma_fc, beta_fc, invG, statsG2);
    // logits = BN(g2) @ W_cls + b_cls -> log_softmax
    head_kernel<<<2, 256, 0, stream>>>(g2, statsG2, gamma_h, beta_h, W_cls, b_cls, out, invG);
}